// Round 1
// baseline (11350.962 us; speedup 1.0000x reference)
//
#include <hip/hip_runtime.h>
#include <math.h>

// Problem constants
#define BB   8
#define TT   12
#define CIN  64
#define HID  128
#define CTOT 192
#define NCLS 5
// ws layout (float offsets)
#define OFF_WT   0ull            // 192*9*512 = 884736
#define OFF_WCT  884736ull       // 128*9*8   = 9216
#define OFF_C    893952ull       // 4194304
#define OFF_HA   5088256ull      // 4194304
#define OFF_HB   9282560ull      // 4194304

__global__ __launch_bounds__(256) void zero_kernel(float* __restrict__ p, int n4) {
    int i = blockIdx.x * blockDim.x + threadIdx.x;
    int stride = gridDim.x * blockDim.x;
    float4* p4 = (float4*)p;
    for (; i < n4; i += stride) p4[i] = make_float4(0.f, 0.f, 0.f, 0.f);
}

// w_lstm (512,192,3,3) -> wT[(ci*9+tap)*512 + co]
__global__ __launch_bounds__(256) void wt_transform(const float* __restrict__ w,
                                                    float* __restrict__ wT) {
    int idx = blockIdx.x * 256 + threadIdx.x;
    if (idx >= 512 * 192 * 9) return;
    int co = idx & 511;
    int r  = idx >> 9;            // ci*9 + tap
    int ci = r / 9, tap = r - ci * 9;
    wT[idx] = w[co * 1728 + ci * 9 + tap];
}

// w_conv (5,128,3,3) -> wcT[(ci*9+tap)*8 + cls], cls padded to 8
__global__ __launch_bounds__(256) void wc_transform(const float* __restrict__ w,
                                                    float* __restrict__ wcT) {
    int idx = blockIdx.x * 256 + threadIdx.x;
    if (idx >= 128 * 9 * 8) return;
    int cls = idx & 7;
    int r   = idx >> 3;           // ci*9 + tap
    wcT[idx] = (cls < 5) ? w[cls * 1152 + r] : 0.f;
}

// Fused: gates conv (3x3 SAME, concat(x_t,h) -> 4*HID) + LSTM pointwise.
// Block: 16x16 spatial tile of one batch, 8 hidden channels x 4 gates.
__global__ __launch_bounds__(256) void clstm_step(
    const float* __restrict__ x, const float* __restrict__ h_in,
    const float* __restrict__ wT, const float* __restrict__ b_lstm,
    float* __restrict__ c_st, float* __restrict__ h_out, int t)
{
    __shared__ float smem[10368];     // s_in [16][18][20] = 5760 | s_w [16][9][32] = 4608
    float* s_in = smem;
    float* s_w  = smem + 5760;

    const int tid = threadIdx.x;
    const int bid = blockIdx.x;
    const int hcb = bid & 15;                 // hidden-channel block (8 ch each)
    const int tb  = (bid >> 4) & 15;          // spatial tile
    const int b   = bid >> 8;
    const int y0  = (tb >> 2) << 4;
    const int x0  = (tb & 3) << 4;
    const int hc0 = hcb << 3;

    const int g  = tid & 3;                   // gate index (i,f,o,g)
    const int sg = tid >> 2;                  // spatial group 0..63
    const int ry = sg >> 2;                   // tile row 0..15
    const int xq = (sg & 3) << 2;             // tile col start (x4)

    float acc[8][4];
    #pragma unroll
    for (int j = 0; j < 8; ++j)
        #pragma unroll
        for (int p = 0; p < 4; ++p) acc[j][p] = 0.f;

    #pragma unroll 1
    for (int cc = 0; cc < 12; ++cc) {
        const float* src = (cc < 4)
            ? x    + ((size_t)(b * TT + t) * CIN + cc * 16) * 4096
            : h_in + ((size_t)b * HID + (cc * 16 - 64)) * 4096;
        // stage input tile: 16 ci x 18 x 18 (zero-padded halo)
        for (int idx = tid; idx < 5184; idx += 256) {
            int ci_l = idx / 324;
            int r    = idx - ci_l * 324;
            int iy   = r / 18;
            int ix   = r - iy * 18;
            int gy = y0 + iy - 1, gx = x0 + ix - 1;
            float v = 0.f;
            if ((unsigned)gy < 64u && (unsigned)gx < 64u)
                v = src[ci_l * 4096 + gy * 64 + gx];
            s_in[ci_l * 360 + iy * 20 + ix] = v;
        }
        // stage weights: 16 ci x 9 taps x 32 co  (co_l = g*8 + j)
        const int ci0 = cc * 16;
        for (int idx = tid; idx < 4608; idx += 256) {
            int co_l = idx & 31;
            int r    = idx >> 5;              // ci_l*9 + tap
            int tap  = r % 9;
            int ci_l = r / 9;
            int co_g = (co_l >> 3) * 128 + hc0 + (co_l & 7);
            s_w[ci_l * 288 + tap * 32 + co_l] = wT[((size_t)(ci0 + ci_l) * 9 + tap) * 512 + co_g];
        }
        __syncthreads();
        #pragma unroll 1
        for (int ci_l = 0; ci_l < 16; ++ci_l) {
            #pragma unroll
            for (int ky = 0; ky < 3; ++ky) {
                const float* rp = &s_in[ci_l * 360 + (ry + ky) * 20 + xq];
                float4 a0 = *(const float4*)rp;
                float2 a1 = *(const float2*)(rp + 4);
                float in6[6] = {a0.x, a0.y, a0.z, a0.w, a1.x, a1.y};
                #pragma unroll
                for (int kx = 0; kx < 3; ++kx) {
                    const float* wp = &s_w[ci_l * 288 + (ky * 3 + kx) * 32 + g * 8];
                    float4 w0 = *(const float4*)wp;
                    float4 w1 = *(const float4*)(wp + 4);
                    float wv[8] = {w0.x, w0.y, w0.z, w0.w, w1.x, w1.y, w1.z, w1.w};
                    #pragma unroll
                    for (int j = 0; j < 8; ++j)
                        #pragma unroll
                        for (int p = 0; p < 4; ++p)
                            acc[j][p] = fmaf(wv[j], in6[kx + p], acc[j][p]);
                }
            }
        }
        __syncthreads();
    }

    // epilogue: exchange 4 gates via LDS (row stride 258 to spread banks)
    #pragma unroll
    for (int j = 0; j < 8; ++j)
        #pragma unroll
        for (int p = 0; p < 4; ++p)
            smem[(g * 8 + j) * 258 + sg * 4 + p] = acc[j][p];
    __syncthreads();

    #pragma unroll
    for (int k = 0; k < 8; ++k) {
        int item = tid + k * 256;
        int hc_l = item >> 8;                 // 0..7
        int pos  = item & 255;                // 0..255 in tile
        float vi = smem[(0 * 8 + hc_l) * 258 + pos] + b_lstm[      hc0 + hc_l];
        float vf = smem[(1 * 8 + hc_l) * 258 + pos] + b_lstm[128 + hc0 + hc_l];
        float vo = smem[(2 * 8 + hc_l) * 258 + pos] + b_lstm[256 + hc0 + hc_l];
        float vg = smem[(3 * 8 + hc_l) * 258 + pos] + b_lstm[384 + hc0 + hc_l];
        float i_ = 1.f / (1.f + __expf(-vi));
        float f_ = 1.f / (1.f + __expf(-vf));
        float o_ = 1.f / (1.f + __expf(-vo));
        float g_ = tanhf(vg);
        size_t cidx = ((size_t)b * HID + hc0 + hc_l) * 4096
                    + (size_t)(y0 + (pos >> 4)) * 64 + x0 + (pos & 15);
        float cv = f_ * c_st[cidx] + i_ * g_;
        c_st[cidx]  = cv;
        h_out[cidx] = o_ * tanhf(cv);
    }
}

// Final 3x3 conv (128 -> 5) + channelwise log_softmax
__global__ __launch_bounds__(256) void final_conv(
    const float* __restrict__ h, const float* __restrict__ wcT,
    const float* __restrict__ b_conv, float* __restrict__ out)
{
    __shared__ float s_wc[9216];
    for (int idx = threadIdx.x; idx < 9216; idx += 256) s_wc[idx] = wcT[idx];
    __syncthreads();
    int pos = blockIdx.x * 256 + threadIdx.x;     // 32768 positions
    int b = pos >> 12;
    int r = pos & 4095;
    int y = r >> 6;
    int x = r & 63;
    float acc[5];
    #pragma unroll
    for (int cls = 0; cls < 5; ++cls) acc[cls] = b_conv[cls];
    const float* hb = h + (size_t)b * HID * 4096;
    #pragma unroll 1
    for (int ci = 0; ci < 128; ++ci) {
        const float* hc = hb + ci * 4096;
        #pragma unroll
        for (int ky = 0; ky < 3; ++ky) {
            int gy = y + ky - 1;
            bool rowok = (unsigned)gy < 64u;
            float hv[3];
            #pragma unroll
            for (int kx = 0; kx < 3; ++kx) {
                int gx = x + kx - 1;
                hv[kx] = (rowok && (unsigned)gx < 64u) ? hc[gy * 64 + gx] : 0.f;
            }
            #pragma unroll
            for (int kx = 0; kx < 3; ++kx) {
                const float* wp = &s_wc[(ci * 9 + ky * 3 + kx) * 8];
                float4 w0 = *(const float4*)wp;
                float  w4 = wp[4];
                acc[0] = fmaf(hv[kx], w0.x, acc[0]);
                acc[1] = fmaf(hv[kx], w0.y, acc[1]);
                acc[2] = fmaf(hv[kx], w0.z, acc[2]);
                acc[3] = fmaf(hv[kx], w0.w, acc[3]);
                acc[4] = fmaf(hv[kx], w4,   acc[4]);
            }
        }
    }
    float m = acc[0];
    #pragma unroll
    for (int cls = 1; cls < 5; ++cls) m = fmaxf(m, acc[cls]);
    float s = 0.f;
    #pragma unroll
    for (int cls = 0; cls < 5; ++cls) s += __expf(acc[cls] - m);
    float lse = logf(s) + m;
    #pragma unroll
    for (int cls = 0; cls < 5; ++cls)
        out[((size_t)(b * 5 + cls) << 12) + (y << 6) + x] = acc[cls] - lse;
}

extern "C" void kernel_launch(void* const* d_in, const int* in_sizes, int n_in,
                              void* d_out, int out_size, void* d_ws, size_t ws_size,
                              hipStream_t stream) {
    const float* x      = (const float*)d_in[0];
    const float* w_lstm = (const float*)d_in[1];
    const float* b_lstm = (const float*)d_in[2];
    const float* w_conv = (const float*)d_in[3];
    const float* b_conv = (const float*)d_in[4];
    float* ws  = (float*)d_ws;
    float* wT  = ws + OFF_WT;
    float* wcT = ws + OFF_WCT;
    float* c   = ws + OFF_C;
    float* hA  = ws + OFF_HA;
    float* hB  = ws + OFF_HB;

    // zero c and hA (contiguous, 2*4194304 floats)
    zero_kernel<<<2048, 256, 0, stream>>>(c, (2 * 4194304) / 4);
    wt_transform<<<(512 * 192 * 9 + 255) / 256, 256, 0, stream>>>(w_lstm, wT);
    wc_transform<<<(128 * 9 * 8 + 255) / 256, 256, 0, stream>>>(w_conv, wcT);

    for (int t = 0; t < TT; ++t) {
        const float* h_in = (t & 1) ? hB : hA;
        float*       h_out = (t & 1) ? hA : hB;
        clstm_step<<<BB * 16 * 16, 256, 0, stream>>>(x, h_in, wT, b_lstm, c, h_out, t);
    }
    final_conv<<<128, 256, 0, stream>>>(hA, wcT, b_conv, (float*)d_out);
}

// Round 5
// 1351.499 us; speedup vs baseline: 8.3988x; 8.3988x over previous
//
#include <hip/hip_runtime.h>
#include <math.h>

#define BB   8
#define TT   12

typedef _Float16 f16;
typedef f16  f16x8 __attribute__((ext_vector_type(8)));
typedef float f32x4 __attribute__((ext_vector_type(4)));

// ws layout (byte offsets) — halo image is 66*68 = 4488 positions (FIXED from 4482)
#define OFF_WT2  0ull            // 8*6*64*296*2        = 1,818,624
#define OFF_WC   1818624ull      // 9*128*8*4           = 36,864    -> 1,855,488
#define OFF_XP   1855488ull      // 8*66*68*64*2        = 4,595,712 -> 6,451,200
#define OFF_HA   6451200ull      // 8*66*68*128*2       = 9,191,424 -> 15,642,624
#define OFF_HB   15642624ull     // 9,191,424           -> 24,834,048
#define OFF_C    24834048ull     // 8*64*64*128*4       = 16,777,216 -> 41,611,264
#define WS_END   41611264ull
#define ZERO_BYTES (WS_END - OFF_XP)   // xp + hA + hB + c = 39,755,776

__device__ inline void gload16(const void* g, void* l) {
    // l must be the WAVE-UNIFORM base; HW adds lane*16.
    __builtin_amdgcn_global_load_lds((const __attribute__((address_space(1))) void*)g,
                                     (__attribute__((address_space(3))) void*)l, 16, 0, 0);
}

__global__ __launch_bounds__(256) void zero_kernel(float4* __restrict__ p, int n4) {
    int i = blockIdx.x * blockDim.x + threadIdx.x;
    int stride = gridDim.x * blockDim.x;
    for (; i < n4; i += stride) p[i] = make_float4(0.f, 0.f, 0.f, 0.f);
}

// w_lstm (512,192,3,3) fp32 -> wT2 f16 [ntile(8)][chunk(6)][co_l(64)][k(296 pad)]
// co' = hid*4+gate, k = tap*32 + ci_l (k>=288 zero pad)
__global__ __launch_bounds__(256) void wprep(const float* __restrict__ w, f16* __restrict__ wT2) {
    int t = blockIdx.x * 256 + threadIdx.x;
    if (t >= 8 * 6 * 64 * 296) return;
    int k    = t % 296;
    int r    = t / 296;
    int co_l = r & 63;
    int r2   = r >> 6;
    int chunk = r2 % 6;
    int ntl   = r2 / 6;
    f16 val = (f16)0.f;
    if (k < 288) {
        int tap = k >> 5, ci_l = k & 31;
        int ci  = chunk * 32 + ci_l;          // concat(x:0..63, h:64..191) order
        int cop = ntl * 64 + co_l;
        int hid = cop >> 2, gate = cop & 3;
        val = (f16)w[((size_t)(gate * 128 + hid) * 192 + ci) * 9 + tap];
    }
    wT2[t] = val;
}

// w_conv (5,128,3,3) -> wc f32 [tap(9)][ci(128)][8] (cls padded)
__global__ __launch_bounds__(256) void wcprep(const float* __restrict__ w, float* __restrict__ wc) {
    int t = blockIdx.x * 256 + threadIdx.x;
    if (t >= 9216) return;
    int cls = t & 7, ci = (t >> 3) & 127, tap = t >> 10;
    wc[t] = (cls < 5) ? w[(size_t)(cls * 128 + ci) * 9 + tap] : 0.f;
}

// x_t NCHW fp32 -> NHWC f16 with halo: xp[b][y+1][x+1][ci], dims [8][66][68][64]
__global__ __launch_bounds__(256) void xprep(const float* __restrict__ x, f16* __restrict__ xp, int t) {
    int pos = blockIdx.x * 256 + threadIdx.x;     // 32768
    int b = pos >> 12, rr = pos & 4095, y = rr >> 6, xx = rr & 63;
    const float* s = x + ((size_t)(b * TT + t) * 64) * 4096 + y * 64 + xx;
    f16* d = xp + (((size_t)b * 66 + y + 1) * 68 + xx + 1) * 64;
    #pragma unroll
    for (int c8 = 0; c8 < 8; ++c8) {
        f16x8 v;
        #pragma unroll
        for (int e = 0; e < 8; ++e) v[e] = (f16)s[(size_t)(c8 * 8 + e) * 4096];
        *(f16x8*)&d[c8 * 8] = v;
    }
}

__device__ inline float pickc(f32x4 v, int j) {
    return j == 0 ? v[0] : j == 1 ? v[1] : j == 2 ? v[2] : v[3];
}

// Fused gates-GEMM (implicit im2col, f16 MFMA) + LSTM pointwise epilogue.
// Block: 128 pos (2 image rows) x 64 co'. 4 waves of 64x32.
__global__ __launch_bounds__(256, 2) void gemm_step(
    const f16* __restrict__ xp, const f16* __restrict__ hin,
    const f16* __restrict__ wT2, const float* __restrict__ b_lstm,
    float* __restrict__ c_st, f16* __restrict__ hout)
{
    __shared__ __align__(16) char smem[59008];
    f16* As = (f16*)smem;            // [264 pos][40 f16] = 21120 B
    f16* Bs = (f16*)(smem + 21120);  // [64 co][296 k]    = 37888 B

    const int tid  = threadIdx.x;
    const int lane = tid & 63;
    const int wid  = tid >> 6;
    const int wr   = wid >> 1, wc = wid & 1;
    const int l15  = lane & 15, lg = lane >> 4;

    const int bid = blockIdx.x;
    const int nt  = bid & 7;
    const int mt  = bid >> 3;                 // 0..255
    const int b   = mt >> 5;
    const int y0  = (mt & 31) << 1;           // first image row of tile

    f32x4 acc[4][2] = {};
    const f16* wslice = wT2 + (size_t)(nt * 6) * 18944;

    for (int chunk = 0; chunk < 6; ++chunk) {
        if (chunk) __syncthreads();
        const f16* src; int cst, ci0;
        if (chunk < 2) { src = xp;  cst = 64;  ci0 = chunk * 32; }
        else           { src = hin; cst = 128; ci0 = chunk * 32 - 64; }
        const size_t rowbase = ((size_t)b * 66 + y0) * 68;
        // ---- stage A (reg path, NHWC source is contiguous along ci) ----
        #pragma unroll
        for (int i = 0; i < 5; ++i) {
            int idx = i * 256 + tid;
            if (idx < 1056) {
                int ci8 = idx & 3;
                int pc  = idx >> 2;                 // 0..263 = r*66+c
                int r   = (pc * 497) >> 15;         // /66 exact for pc<264
                int c   = pc - r * 66;
                const f16* s = src + (rowbase + (size_t)r * 68 + c) * cst + ci0 + ci8 * 8;
                *(f16x8*)&As[pc * 40 + ci8 * 8] = *(const f16x8*)s;
            }
        }
        // ---- stage B via global_load_lds (wave-uniform LDS base, lane*16 by HW) ----
        const char* bsrc = (const char*)(wslice + (size_t)chunk * 18944);
        for (int k = wid; k < 37; k += 4) {
            int off = k * 1024;                     // 37*1024 = 37888 = B bytes
            gload16(bsrc + off + lane * 16, ((char*)Bs) + off);
        }
        __syncthreads();
        // ---- compute: 9 taps x (4x2 frags) ----
        #pragma unroll
        for (int tap = 0; tap < 9; ++tap) {
            const int dy = tap / 3, dx = tap - dy * 3;
            f16x8 a[4];
            #pragma unroll
            for (int mf = 0; mf < 4; ++mf) {
                int p = (wr + dy) * 66 + mf * 16 + l15 + dx;
                a[mf] = *(const f16x8*)&As[p * 40 + lg * 8];
            }
            f16x8 bf[2];
            #pragma unroll
            for (int nf = 0; nf < 2; ++nf) {
                int co = wc * 32 + nf * 16 + l15;
                bf[nf] = *(const f16x8*)&Bs[co * 296 + tap * 32 + lg * 8];
            }
            #pragma unroll
            for (int mf = 0; mf < 4; ++mf)
                #pragma unroll
                for (int nf = 0; nf < 2; ++nf)
                    acc[mf][nf] = __builtin_amdgcn_mfma_f32_16x16x32_f16(a[mf], bf[nf], acc[mf][nf], 0, 0, 0);
        }
    }

    // ---- LSTM epilogue: 4-gate exchange via shfl_xor within 4-lane groups ----
    const int q = lane & 3;   // = gate index of this lane's column (co' = hid*4+gate)
    #pragma unroll
    for (int mf = 0; mf < 4; ++mf) {
        #pragma unroll
        for (int nf = 0; nf < 2; ++nf) {
            int hid = nt * 16 + wc * 8 + nf * 4 + (l15 >> 2);
            float bias = b_lstm[q * 128 + hid];
            f32x4 v = acc[mf][nf];
            v[0] += bias; v[1] += bias; v[2] += bias; v[3] += bias;
            float own = pickc(v, q);
            float r1 = __shfl_xor(pickc(v, q ^ 1), 1);
            float r2 = __shfl_xor(pickc(v, q ^ 2), 2);
            float r3 = __shfl_xor(pickc(v, q ^ 3), 3);
            float gi = q == 0 ? own : (q == 1 ? r1 : q == 2 ? r2 : r3);
            float gf = q == 1 ? own : (q == 0 ? r1 : q == 3 ? r2 : r3);
            float go = q == 2 ? own : (q == 3 ? r1 : q == 0 ? r2 : r3);
            float gg = q == 3 ? own : (q == 2 ? r1 : q == 1 ? r2 : r3);
            float i_ = 1.f / (1.f + __expf(-gi));
            float f_ = 1.f / (1.f + __expf(-gf));
            float o_ = 1.f / (1.f + __expf(-go));
            float g_ = tanhf(gg);
            int pos_img = wr * 64 + mf * 16 + lg * 4 + q;       // C row = lg*4 + reg(q)
            int py = y0 + (pos_img >> 6);
            int px = pos_img & 63;
            size_t ic = (((size_t)b * 64 + py) * 64 + px) * 128 + hid;
            float cv = f_ * c_st[ic] + i_ * g_;
            c_st[ic] = cv;
            float hv = o_ * tanhf(cv);
            hout[(((size_t)b * 66 + py + 1) * 68 + (px + 1)) * 128 + hid] = (f16)hv;
        }
    }
}

// Final 3x3 conv (128 -> 5) over NHWC f16 h + channelwise log_softmax (NCHW out)
__global__ __launch_bounds__(256) void final_conv(
    const f16* __restrict__ h, const float* __restrict__ wc,
    const float* __restrict__ b_conv, float* __restrict__ out)
{
    __shared__ float swc[9216];
    for (int i = threadIdx.x; i < 9216; i += 256) swc[i] = wc[i];
    __syncthreads();
    int pos = blockIdx.x * 256 + threadIdx.x;
    int b = pos >> 12, rr = pos & 4095, y = rr >> 6, xx = rr & 63;
    float acc[5];
    #pragma unroll
    for (int cls = 0; cls < 5; ++cls) acc[cls] = b_conv[cls];
    #pragma unroll 1
    for (int tap = 0; tap < 9; ++tap) {
        int dy = tap / 3, dx = tap - dy * 3;
        const f16* hp = h + (((size_t)b * 66 + y + dy) * 68 + xx + dx) * 128;
        #pragma unroll
        for (int c16 = 0; c16 < 16; ++c16) {
            f16x8 v = *(const f16x8*)&hp[c16 * 8];
            #pragma unroll
            for (int e = 0; e < 8; ++e) {
                float hv = (float)v[e];
                const float* wp = &swc[(size_t)(tap * 128 + c16 * 8 + e) * 8];
                acc[0] = fmaf(hv, wp[0], acc[0]);
                acc[1] = fmaf(hv, wp[1], acc[1]);
                acc[2] = fmaf(hv, wp[2], acc[2]);
                acc[3] = fmaf(hv, wp[3], acc[3]);
                acc[4] = fmaf(hv, wp[4], acc[4]);
            }
        }
    }
    float m = acc[0];
    #pragma unroll
    for (int cls = 1; cls < 5; ++cls) m = fmaxf(m, acc[cls]);
    float s = 0.f;
    #pragma unroll
    for (int cls = 0; cls < 5; ++cls) s += __expf(acc[cls] - m);
    float lse = logf(s) + m;
    #pragma unroll
    for (int cls = 0; cls < 5; ++cls)
        out[((size_t)(b * 5 + cls) << 12) + (y << 6) + xx] = acc[cls] - lse;
}

extern "C" void kernel_launch(void* const* d_in, const int* in_sizes, int n_in,
                              void* d_out, int out_size, void* d_ws, size_t ws_size,
                              hipStream_t stream) {
    const float* x      = (const float*)d_in[0];
    const float* w_lstm = (const float*)d_in[1];
    const float* b_lstm = (const float*)d_in[2];
    const float* w_conv = (const float*)d_in[3];
    const float* b_conv = (const float*)d_in[4];
    char* ws = (char*)d_ws;
    f16*   wT2 = (f16*)(ws + OFF_WT2);
    float* wc  = (float*)(ws + OFF_WC);
    f16*   xp  = (f16*)(ws + OFF_XP);
    f16*   hA  = (f16*)(ws + OFF_HA);
    f16*   hB  = (f16*)(ws + OFF_HB);
    float* c   = (float*)(ws + OFF_C);

    zero_kernel<<<2048, 256, 0, stream>>>((float4*)(ws + OFF_XP), (int)(ZERO_BYTES / 16));
    wprep<<<3552, 256, 0, stream>>>(w_lstm, wT2);
    wcprep<<<36, 256, 0, stream>>>(w_conv, wc);

    for (int t = 0; t < TT; ++t) {
        const f16* hin  = (t & 1) ? hB : hA;
        f16*       hout = (t & 1) ? hA : hB;
        xprep<<<128, 256, 0, stream>>>(x, xp, t);
        gemm_step<<<2048, 256, 0, stream>>>(xp, hin, wT2, b_lstm, c, hout);
    }
    final_conv<<<128, 256, 0, stream>>>(hA, wc, b_conv, (float*)d_out);
}

// Round 6
// 1200.002 us; speedup vs baseline: 9.4591x; 1.1262x over previous
//
#include <hip/hip_runtime.h>
#include <math.h>

#define BB   8
#define TT   12

typedef _Float16 f16;
typedef f16  f16x8 __attribute__((ext_vector_type(8)));
typedef float f32x4 __attribute__((ext_vector_type(4)));

// ws layout (byte offsets) — halo image is 66*68 = 4488 positions
#define OFF_WT2  0ull            // 8*6*64*296*2        = 1,818,624
#define OFF_WC   1818624ull      // 9*128*8*4           = 36,864    -> 1,855,488
#define OFF_XP   1855488ull      // 8*66*68*64*2        = 4,595,712 -> 6,451,200
#define OFF_HA   6451200ull      // 8*66*68*128*2       = 9,191,424 -> 15,642,624
#define OFF_HB   15642624ull     // 9,191,424           -> 24,834,048
#define OFF_C    24834048ull     // 8*64*64*128*4       = 16,777,216 -> 41,611,264
#define WS_END   41611264ull
#define ZERO_BYTES (WS_END - OFF_XP)   // xp + hA + hB + c = 39,755,776

#define A_BYTES 31680            // 396 pos * 40 f16 * 2B
#define B_BYTES 37888            // 64 co * 296 k * 2B

__device__ inline void gload16(const void* g, void* l) {
    // LDS dest is the WAVE-UNIFORM base; HW adds lane*16.
    __builtin_amdgcn_global_load_lds((const __attribute__((address_space(1))) void*)g,
                                     (__attribute__((address_space(3))) void*)l, 16, 0, 0);
}

__global__ __launch_bounds__(256) void zero_kernel(float4* __restrict__ p, int n4) {
    int i = blockIdx.x * blockDim.x + threadIdx.x;
    int stride = gridDim.x * blockDim.x;
    for (; i < n4; i += stride) p[i] = make_float4(0.f, 0.f, 0.f, 0.f);
}

// w_lstm (512,192,3,3) fp32 -> wT2 f16 [ntile(8)][chunk(6)][co_l(64)][k(296 pad)]
// co' = hid*4+gate, k = tap*32 + ci_l (k>=288 zero pad)
__global__ __launch_bounds__(256) void wprep(const float* __restrict__ w, f16* __restrict__ wT2) {
    int t = blockIdx.x * 256 + threadIdx.x;
    if (t >= 8 * 6 * 64 * 296) return;
    int k    = t % 296;
    int r    = t / 296;
    int co_l = r & 63;
    int r2   = r >> 6;
    int chunk = r2 % 6;
    int ntl   = r2 / 6;
    f16 val = (f16)0.f;
    if (k < 288) {
        int tap = k >> 5, ci_l = k & 31;
        int ci  = chunk * 32 + ci_l;          // concat(x:0..63, h:64..191) order
        int cop = ntl * 64 + co_l;
        int hid = cop >> 2, gate = cop & 3;
        val = (f16)w[((size_t)(gate * 128 + hid) * 192 + ci) * 9 + tap];
    }
    wT2[t] = val;
}

// w_conv (5,128,3,3) -> wc f32 [tap(9)][ci(128)][8] (cls padded)
__global__ __launch_bounds__(256) void wcprep(const float* __restrict__ w, float* __restrict__ wc) {
    int t = blockIdx.x * 256 + threadIdx.x;
    if (t >= 9216) return;
    int cls = t & 7, ci = (t >> 3) & 127, tap = t >> 10;
    wc[t] = (cls < 5) ? w[(size_t)(cls * 128 + ci) * 9 + tap] : 0.f;
}

// x_t NCHW fp32 -> NHWC f16 with halo: xp[b][y+1][x+1][ci], dims [8][66][68][64]
__global__ __launch_bounds__(256) void xprep(const float* __restrict__ x, f16* __restrict__ xp, int t) {
    int pos = blockIdx.x * 256 + threadIdx.x;     // 32768
    int b = pos >> 12, rr = pos & 4095, y = rr >> 6, xx = rr & 63;
    const float* s = x + ((size_t)(b * TT + t) * 64) * 4096 + y * 64 + xx;
    f16* d = xp + (((size_t)b * 66 + y + 1) * 68 + xx + 1) * 64;
    #pragma unroll
    for (int c8 = 0; c8 < 8; ++c8) {
        f16x8 v;
        #pragma unroll
        for (int e = 0; e < 8; ++e) v[e] = (f16)s[(size_t)(c8 * 8 + e) * 4096];
        *(f16x8*)&d[c8 * 8] = v;
    }
}

__device__ inline float pickc(f32x4 v, int j) {
    return j == 0 ? v[0] : j == 1 ? v[1] : j == 2 ? v[2] : v[3];
}

// Fused gates-GEMM (implicit im2col, f16 MFMA) + LSTM pointwise epilogue.
// Block: 256 pos (4 image rows) x 64 co'. 8 waves of 64x32. 2-phase pipeline:
// chunk c+1's A-regs + B gload_lds issued before chunk c's compute; one barrier/chunk.
__global__ __launch_bounds__(512, 2) void gemm_step(
    const f16* __restrict__ xp, const f16* __restrict__ hin,
    const f16* __restrict__ wT2, const float* __restrict__ b_lstm,
    float* __restrict__ c_st, f16* __restrict__ hout)
{
    __shared__ __align__(16) char smem[2 * A_BYTES + 2 * B_BYTES];   // 139,136 B
    f16* As0 = (f16*)smem;
    f16* As1 = (f16*)(smem + A_BYTES);
    char* Bs0 = smem + 2 * A_BYTES;
    char* Bs1 = smem + 2 * A_BYTES + B_BYTES;

    const int tid  = threadIdx.x;
    const int lane = tid & 63;
    const int wid  = tid >> 6;                // 0..7
    const int wr   = wid >> 1, wc = wid & 1;  // wr 0..3 (M), wc 0..1 (N)
    const int l15  = lane & 15, lg = lane >> 4;

    const int bid = blockIdx.x;
    const int nt  = bid & 7;
    const int mt  = bid >> 3;                 // 0..127
    const int b   = mt >> 4;
    const int y0  = (mt & 15) << 2;           // first image row of tile (4 rows)

    const size_t rowbase = ((size_t)b * 66 + y0) * 68;
    const f16* wslice = wT2 + (size_t)(nt * 6) * 18944;

    f32x4 acc[4][2] = {};
    f16x8 areg[4];

    // ---- A loader: chunk cc -> regs (1584 items: 396 pos x 4 ci8) ----
    auto loadA = [&](int cc) {
        const f16* src; int cst, ci0;
        if (cc < 2) { src = xp;  cst = 64;  ci0 = cc * 32; }
        else        { src = hin; cst = 128; ci0 = cc * 32 - 64; }
        #pragma unroll
        for (int i = 0; i < 4; ++i) {
            int idx = i * 512 + tid;
            if (idx < 1584) {
                int ci8 = idx & 3;
                int pc  = idx >> 2;                 // 0..395 = r*66+c
                int r   = (pc * 497) >> 15;         // /66 exact for pc<396
                int c   = pc - r * 66;
                areg[i] = *(const f16x8*)(src + (rowbase + (size_t)r * 68 + c) * cst + ci0 + ci8 * 8);
            }
        }
    };
    auto writeA = [&](f16* As) {
        #pragma unroll
        for (int i = 0; i < 4; ++i) {
            int idx = i * 512 + tid;
            if (idx < 1584)
                *(f16x8*)&As[(idx >> 2) * 40 + (idx & 3) * 8] = areg[i];
        }
    };
    auto stageB = [&](int cc, char* Bs) {
        const char* bsrc = (const char*)(wslice + (size_t)cc * 18944);
        for (int k = wid; k < 37; k += 8)           // 37*1024 = 37888 B
            gload16(bsrc + k * 1024 + lane * 16, Bs + k * 1024);
    };

    // ---- prologue: stage chunk 0 ----
    loadA(0);
    stageB(0, Bs0);
    writeA(As0);
    __syncthreads();

    f16* Acur = As0; f16* Aalt = As1;
    char* Bcur = Bs0; char* Balt = Bs1;

    #pragma unroll 1
    for (int cc = 0; cc < 6; ++cc) {
        if (cc < 5) {
            stageB(cc + 1, Balt);     // async into alt buffer (retired at prev barrier)
            loadA(cc + 1);            // global->reg, in flight during compute
        }
        // ---- compute chunk cc: 9 taps x (4x2 frags) ----
        f16* As = Acur; f16* Bsf = (f16*)Bcur;
        #pragma unroll
        for (int tap = 0; tap < 9; ++tap) {
            const int dy = tap / 3, dx = tap - dy * 3;
            f16x8 a[4];
            #pragma unroll
            for (int mf = 0; mf < 4; ++mf) {
                int p = (wr + dy) * 66 + mf * 16 + l15 + dx;
                a[mf] = *(const f16x8*)&As[p * 40 + lg * 8];
            }
            f16x8 bf[2];
            #pragma unroll
            for (int nf = 0; nf < 2; ++nf) {
                int co = wc * 32 + nf * 16 + l15;
                bf[nf] = *(const f16x8*)&Bsf[co * 296 + tap * 32 + lg * 8];
            }
            #pragma unroll
            for (int mf = 0; mf < 4; ++mf)
                #pragma unroll
                for (int nf = 0; nf < 2; ++nf)
                    acc[mf][nf] = __builtin_amdgcn_mfma_f32_16x16x32_f16(a[mf], bf[nf], acc[mf][nf], 0, 0, 0);
        }
        if (cc < 5) writeA(Aalt);     // ds_write prefetched A (vmcnt auto-inserted)
        __syncthreads();              // drains B gload_lds issued a full phase ago
        f16* ta = Acur; Acur = Aalt; Aalt = ta;
        char* tb = Bcur; Bcur = Balt; Balt = tb;
    }

    // ---- LSTM epilogue: 4-gate exchange via shfl_xor within 4-lane groups ----
    const int q = lane & 3;   // = gate index of this lane's column (co' = hid*4+gate)
    #pragma unroll
    for (int mf = 0; mf < 4; ++mf) {
        #pragma unroll
        for (int nf = 0; nf < 2; ++nf) {
            int hid = nt * 16 + wc * 8 + nf * 4 + (l15 >> 2);
            float bias = b_lstm[q * 128 + hid];
            f32x4 v = acc[mf][nf];
            v[0] += bias; v[1] += bias; v[2] += bias; v[3] += bias;
            float own = pickc(v, q);
            float r1 = __shfl_xor(pickc(v, q ^ 1), 1);
            float r2 = __shfl_xor(pickc(v, q ^ 2), 2);
            float r3 = __shfl_xor(pickc(v, q ^ 3), 3);
            float gi = q == 0 ? own : (q == 1 ? r1 : q == 2 ? r2 : r3);
            float gf = q == 1 ? own : (q == 0 ? r1 : q == 3 ? r2 : r3);
            float go = q == 2 ? own : (q == 3 ? r1 : q == 0 ? r2 : r3);
            float gg = q == 3 ? own : (q == 2 ? r1 : q == 1 ? r2 : r3);
            float i_ = 1.f / (1.f + __expf(-gi));
            float f_ = 1.f / (1.f + __expf(-gf));
            float o_ = 1.f / (1.f + __expf(-go));
            float g_ = tanhf(gg);
            int pos_img = wr * 64 + mf * 16 + lg * 4 + q;       // 0..255
            int py = y0 + (pos_img >> 6);
            int px = pos_img & 63;
            size_t ic = (((size_t)b * 64 + py) * 64 + px) * 128 + hid;
            float cv = f_ * c_st[ic] + i_ * g_;
            c_st[ic] = cv;
            float hv = o_ * tanhf(cv);
            hout[(((size_t)b * 66 + py + 1) * 68 + (px + 1)) * 128 + hid] = (f16)hv;
        }
    }
}

// Final 3x3 conv (128 -> 5) over NHWC f16 h + channelwise log_softmax (NCHW out)
__global__ __launch_bounds__(256) void final_conv(
    const f16* __restrict__ h, const float* __restrict__ wc,
    const float* __restrict__ b_conv, float* __restrict__ out)
{
    __shared__ float swc[9216];
    for (int i = threadIdx.x; i < 9216; i += 256) swc[i] = wc[i];
    __syncthreads();
    int pos = blockIdx.x * 256 + threadIdx.x;
    int b = pos >> 12, rr = pos & 4095, y = rr >> 6, xx = rr & 63;
    float acc[5];
    #pragma unroll
    for (int cls = 0; cls < 5; ++cls) acc[cls] = b_conv[cls];
    #pragma unroll 1
    for (int tap = 0; tap < 9; ++tap) {
        int dy = tap / 3, dx = tap - dy * 3;
        const f16* hp = h + (((size_t)b * 66 + y + dy) * 68 + xx + dx) * 128;
        #pragma unroll
        for (int c16 = 0; c16 < 16; ++c16) {
            f16x8 v = *(const f16x8*)&hp[c16 * 8];
            #pragma unroll
            for (int e = 0; e < 8; ++e) {
                float hv = (float)v[e];
                const float* wp = &swc[(size_t)(tap * 128 + c16 * 8 + e) * 8];
                acc[0] = fmaf(hv, wp[0], acc[0]);
                acc[1] = fmaf(hv, wp[1], acc[1]);
                acc[2] = fmaf(hv, wp[2], acc[2]);
                acc[3] = fmaf(hv, wp[3], acc[3]);
                acc[4] = fmaf(hv, wp[4], acc[4]);
            }
        }
    }
    float m = acc[0];
    #pragma unroll
    for (int cls = 1; cls < 5; ++cls) m = fmaxf(m, acc[cls]);
    float s = 0.f;
    #pragma unroll
    for (int cls = 0; cls < 5; ++cls) s += __expf(acc[cls] - m);
    float lse = logf(s) + m;
    #pragma unroll
    for (int cls = 0; cls < 5; ++cls)
        out[((size_t)(b * 5 + cls) << 12) + (y << 6) + xx] = acc[cls] - lse;
}

extern "C" void kernel_launch(void* const* d_in, const int* in_sizes, int n_in,
                              void* d_out, int out_size, void* d_ws, size_t ws_size,
                              hipStream_t stream) {
    const float* x      = (const float*)d_in[0];
    const float* w_lstm = (const float*)d_in[1];
    const float* b_lstm = (const float*)d_in[2];
    const float* w_conv = (const float*)d_in[3];
    const float* b_conv = (const float*)d_in[4];
    char* ws = (char*)d_ws;
    f16*   wT2 = (f16*)(ws + OFF_WT2);
    float* wc  = (float*)(ws + OFF_WC);
    f16*   xp  = (f16*)(ws + OFF_XP);
    f16*   hA  = (f16*)(ws + OFF_HA);
    f16*   hB  = (f16*)(ws + OFF_HB);
    float* c   = (float*)(ws + OFF_C);

    zero_kernel<<<2048, 256, 0, stream>>>((float4*)(ws + OFF_XP), (int)(ZERO_BYTES / 16));
    wprep<<<3552, 256, 0, stream>>>(w_lstm, wT2);
    wcprep<<<36, 256, 0, stream>>>(w_conv, wc);

    for (int t = 0; t < TT; ++t) {
        const f16* hin  = (t & 1) ? hB : hA;
        f16*       hout = (t & 1) ? hA : hB;
        xprep<<<128, 256, 0, stream>>>(x, xp, t);
        gemm_step<<<1024, 512, 0, stream>>>(xp, hin, wT2, b_lstm, c, hout);
    }
    final_conv<<<128, 256, 0, stream>>>(hA, wc, b_conv, (float*)d_out);
}

// Round 8
// 1158.297 us; speedup vs baseline: 9.7997x; 1.0360x over previous
//
#include <hip/hip_runtime.h>
#include <math.h>

#define BB   8
#define TT   12

typedef _Float16 f16;
typedef f16  f16x8 __attribute__((ext_vector_type(8)));
typedef float f32x4 __attribute__((ext_vector_type(4)));

// ws layout (byte offsets) — halo image is 66*68 = 4488 positions
#define OFF_WT2  0ull            // 8*6*64*296*2        = 1,818,624
#define OFF_WC   1818624ull      // 9*128*8*4           = 36,864    -> 1,855,488
#define OFF_XP   1855488ull      // 8*66*68*64*2        = 4,595,712 -> 6,451,200
#define OFF_HA   6451200ull      // 8*66*68*128*2       = 9,191,424 -> 15,642,624
#define OFF_HB   15642624ull     // 9,191,424           -> 24,834,048
#define OFF_C    24834048ull     // 8*64*64*128*4       = 16,777,216 -> 41,611,264
#define WS_END   41611264ull
#define ZERO_BYTES (WS_END - OFF_XP)   // xp + hA + hB + c = 39,755,776

#define A_BYTES 31680            // 396 pos * 40 f16 * 2B
#define B_BYTES 37888            // 64 co * 296 k * 2B

__device__ inline void gload16(const void* g, void* l) {
    // LDS dest is the WAVE-UNIFORM base; HW adds lane*16.
    __builtin_amdgcn_global_load_lds((const __attribute__((address_space(1))) void*)g,
                                     (__attribute__((address_space(3))) void*)l, 16, 0, 0);
}

__device__ inline float sigm_fast(float x) {
    // exp overflow/underflow saturates correctly: 1/(1+inf)=0, 1/(1+0)=1
    return 1.f / (1.f + __expf(-x));
}
__device__ inline float tanh_fast(float x) {
    float xx = fminf(fmaxf(x, -15.f), 15.f);   // clamp so e^(2x) never overflows
    float e = __expf(2.f * xx);
    return (e - 1.f) / (e + 1.f);
}

__global__ __launch_bounds__(256) void zero_kernel(float4* __restrict__ p, int n4) {
    int i = blockIdx.x * blockDim.x + threadIdx.x;
    int stride = gridDim.x * blockDim.x;
    for (; i < n4; i += stride) p[i] = make_float4(0.f, 0.f, 0.f, 0.f);
}

// w_lstm (512,192,3,3) fp32 -> wT2 f16 [ntile(8)][chunk(6)][co_l(64)][k(296 pad)]
// co' = hid*4+gate, k = tap*32 + ci_l (k>=288 zero pad)
__global__ __launch_bounds__(256) void wprep(const float* __restrict__ w, f16* __restrict__ wT2) {
    int t = blockIdx.x * 256 + threadIdx.x;
    if (t >= 8 * 6 * 64 * 296) return;
    int k    = t % 296;
    int r    = t / 296;
    int co_l = r & 63;
    int r2   = r >> 6;
    int chunk = r2 % 6;
    int ntl   = r2 / 6;
    f16 val = (f16)0.f;
    if (k < 288) {
        int tap = k >> 5, ci_l = k & 31;
        int ci  = chunk * 32 + ci_l;          // concat(x:0..63, h:64..191) order
        int cop = ntl * 64 + co_l;
        int hid = cop >> 2, gate = cop & 3;
        val = (f16)w[((size_t)(gate * 128 + hid) * 192 + ci) * 9 + tap];
    }
    wT2[t] = val;
}

// w_conv (5,128,3,3) -> wc f32 [tap(9)][ci(128)][8] (cls padded)
__global__ __launch_bounds__(256) void wcprep(const float* __restrict__ w, float* __restrict__ wc) {
    int t = blockIdx.x * 256 + threadIdx.x;
    if (t >= 9216) return;
    int cls = t & 7, ci = (t >> 3) & 127, tap = t >> 10;
    wc[t] = (cls < 5) ? w[(size_t)(cls * 128 + ci) * 9 + tap] : 0.f;
}

// x_t NCHW fp32 -> NHWC f16 with halo: xp[b][y+1][x+1][ci], dims [8][66][68][64]
__global__ __launch_bounds__(256) void xprep(const float* __restrict__ x, f16* __restrict__ xp, int t) {
    int pos = blockIdx.x * 256 + threadIdx.x;     // 32768
    int b = pos >> 12, rr = pos & 4095, y = rr >> 6, xx = rr & 63;
    const float* s = x + ((size_t)(b * TT + t) * 64) * 4096 + y * 64 + xx;
    f16* d = xp + (((size_t)b * 66 + y + 1) * 68 + xx + 1) * 64;
    #pragma unroll
    for (int c8 = 0; c8 < 8; ++c8) {
        f16x8 v;
        #pragma unroll
        for (int e = 0; e < 8; ++e) v[e] = (f16)s[(size_t)(c8 * 8 + e) * 4096];
        *(f16x8*)&d[c8 * 8] = v;
    }
}

__device__ inline float pickc(f32x4 v, int j) {
    return j == 0 ? v[0] : j == 1 ? v[1] : j == 2 ? v[2] : v[3];
}

// Fused gates-GEMM (implicit im2col, f16 MFMA) + LSTM pointwise epilogue.
// Block: 256 pos (4 image rows) x 64 co'. 8 waves of 64x32. 2-phase pipeline.
// blockIdx remap: nt = bid>>7, mt = bid&127 -> the 8 nt-blocks sharing one
// mt activation slab have indices == mt (mod 8) -> same XCD -> A fetched once/XCD.
__global__ __launch_bounds__(512, 2) void gemm_step(
    const f16* __restrict__ xp, const f16* __restrict__ hin,
    const f16* __restrict__ wT2, const float* __restrict__ b_lstm,
    float* __restrict__ c_st, f16* __restrict__ hout)
{
    __shared__ __align__(16) char smem[2 * A_BYTES + 2 * B_BYTES];   // 139,136 B
    f16* As0 = (f16*)smem;
    f16* As1 = (f16*)(smem + A_BYTES);
    char* Bs0 = smem + 2 * A_BYTES;
    char* Bs1 = smem + 2 * A_BYTES + B_BYTES;

    const int tid  = threadIdx.x;
    const int lane = tid & 63;
    const int wid  = tid >> 6;                // 0..7
    const int wr   = wid >> 1, wc = wid & 1;  // wr 0..3 (M), wc 0..1 (N)
    const int l15  = lane & 15, lg = lane >> 4;

    const int bid = blockIdx.x;
    const int nt  = bid >> 7;                 // 0..7  (XCD-affinity remap)
    const int mt  = bid & 127;                // 0..127
    const int b   = mt >> 4;
    const int y0  = (mt & 15) << 2;           // first image row of tile (4 rows)

    const int rowbase = (b * 66 + y0) * 68;   // halo-image position base (fits int)
    const f16* wslice = wT2 + (size_t)(nt * 6) * 18944;

    f32x4 acc[4][2] = {};
    f16x8 areg[4];

    // ---- hoisted im2col addressing (per-thread, chunk-invariant) ----
    int po[4];    // position offset rowbase + r*68 + c
    int wo[4];    // LDS write offset (f16 units)
    int c8o[4];   // ci8*8
    bool av[4];
    #pragma unroll
    for (int i = 0; i < 4; ++i) {
        int idx = i * 512 + tid;
        av[i] = idx < 1584;
        int ci8 = idx & 3;
        int pc  = idx >> 2;                 // 0..395 = r*66+c
        int r   = (pc * 497) >> 15;         // /66 exact for pc<396
        int c   = pc - r * 66;
        po[i]  = rowbase + r * 68 + c;
        c8o[i] = ci8 * 8;
        wo[i]  = pc * 40 + ci8 * 8;
    }

    auto loadA = [&](int cc) {
        if (cc < 2) {
            const f16* src = xp; int ci0 = cc * 32;
            #pragma unroll
            for (int i = 0; i < 4; ++i)
                if (av[i]) areg[i] = *(const f16x8*)(src + ((size_t)po[i] << 6) + ci0 + c8o[i]);
        } else {
            const f16* src = hin; int ci0 = cc * 32 - 64;
            #pragma unroll
            for (int i = 0; i < 4; ++i)
                if (av[i]) areg[i] = *(const f16x8*)(src + ((size_t)po[i] << 7) + ci0 + c8o[i]);
        }
    };
    auto writeA = [&](f16* As) {
        #pragma unroll
        for (int i = 0; i < 4; ++i)
            if (av[i]) *(f16x8*)&As[wo[i]] = areg[i];
    };
    auto stageB = [&](int cc, char* Bs) {
        const char* bsrc = (const char*)(wslice + (size_t)cc * 18944);
        for (int k = wid; k < 37; k += 8)           // 37*1024 = 37888 B
            gload16(bsrc + k * 1024 + lane * 16, Bs + k * 1024);
    };

    // ---- prologue: stage chunk 0 ----
    loadA(0);
    stageB(0, Bs0);
    writeA(As0);
    __syncthreads();

    f16* Acur = As0; f16* Aalt = As1;
    char* Bcur = Bs0; char* Balt = Bs1;

    #pragma unroll 1
    for (int cc = 0; cc < 6; ++cc) {
        if (cc < 5) {
            stageB(cc + 1, Balt);     // async into alt buffer (retired at prev barrier)
            loadA(cc + 1);            // global->reg, in flight during compute
        }
        // ---- compute chunk cc: 9 taps x (4x2 frags) ----
        f16* As = Acur; f16* Bsf = (f16*)Bcur;
        #pragma unroll
        for (int tap = 0; tap < 9; ++tap) {
            const int dy = tap / 3, dx = tap - dy * 3;
            f16x8 a[4];
            #pragma unroll
            for (int mf = 0; mf < 4; ++mf) {
                int p = (wr + dy) * 66 + mf * 16 + l15 + dx;
                a[mf] = *(const f16x8*)&As[p * 40 + lg * 8];
            }
            f16x8 bf[2];
            #pragma unroll
            for (int nf = 0; nf < 2; ++nf) {
                int co = wc * 32 + nf * 16 + l15;
                bf[nf] = *(const f16x8*)&Bsf[co * 296 + tap * 32 + lg * 8];
            }
            #pragma unroll
            for (int mf = 0; mf < 4; ++mf)
                #pragma unroll
                for (int nf = 0; nf < 2; ++nf)
                    acc[mf][nf] = __builtin_amdgcn_mfma_f32_16x16x32_f16(a[mf], bf[nf], acc[mf][nf], 0, 0, 0);
        }
        if (cc < 5) writeA(Aalt);     // ds_write prefetched A (vmcnt auto-inserted)
        __syncthreads();              // drains B gload_lds issued a full phase ago
        f16* ta = Acur; Acur = Aalt; Aalt = ta;
        char* tb = Bcur; Bcur = Balt; Balt = tb;
    }

    // ---- LSTM epilogue: 4-gate exchange via shfl_xor within 4-lane groups ----
    const int q = lane & 3;   // = gate index of this lane's column (co' = hid*4+gate)
    #pragma unroll
    for (int mf = 0; mf < 4; ++mf) {
        #pragma unroll
        for (int nf = 0; nf < 2; ++nf) {
            int hid = nt * 16 + wc * 8 + nf * 4 + (l15 >> 2);
            float bias = b_lstm[q * 128 + hid];
            f32x4 v = acc[mf][nf];
            v[0] += bias; v[1] += bias; v[2] += bias; v[3] += bias;
            float own = pickc(v, q);
            float r1 = __shfl_xor(pickc(v, q ^ 1), 1);
            float r2 = __shfl_xor(pickc(v, q ^ 2), 2);
            float r3 = __shfl_xor(pickc(v, q ^ 3), 3);
            float gi = q == 0 ? own : (q == 1 ? r1 : q == 2 ? r2 : r3);
            float gf = q == 1 ? own : (q == 0 ? r1 : q == 3 ? r2 : r3);
            float go = q == 2 ? own : (q == 3 ? r1 : q == 0 ? r2 : r3);
            float gg = q == 3 ? own : (q == 2 ? r1 : q == 1 ? r2 : r3);
            float i_ = sigm_fast(gi);
            float f_ = sigm_fast(gf);
            float o_ = sigm_fast(go);
            float g_ = tanh_fast(gg);
            int pos_img = wr * 64 + mf * 16 + lg * 4 + q;       // 0..255
            int py = y0 + (pos_img >> 6);
            int px = pos_img & 63;
            size_t ic = (((size_t)b * 64 + py) * 64 + px) * 128 + hid;
            float cv = f_ * c_st[ic] + i_ * g_;
            c_st[ic] = cv;
            float hv = o_ * tanh_fast(cv);
            hout[(((size_t)b * 66 + py + 1) * 68 + (px + 1)) * 128 + hid] = (f16)hv;
        }
    }
}

// Final 3x3 conv (128 -> 5) over NHWC f16 h + channelwise log_softmax (NCHW out)
__global__ __launch_bounds__(256) void final_conv(
    const f16* __restrict__ h, const float* __restrict__ wc,
    const float* __restrict__ b_conv, float* __restrict__ out)
{
    __shared__ float swc[9216];
    for (int i = threadIdx.x; i < 9216; i += 256) swc[i] = wc[i];
    __syncthreads();
    int pos = blockIdx.x * 256 + threadIdx.x;
    int b = pos >> 12, rr = pos & 4095, y = rr >> 6, xx = rr & 63;
    float acc[5];
    #pragma unroll
    for (int cls = 0; cls < 5; ++cls) acc[cls] = b_conv[cls];
    #pragma unroll 1
    for (int tap = 0; tap < 9; ++tap) {
        int dy = tap / 3, dx = tap - dy * 3;
        const f16* hp = h + (((size_t)b * 66 + y + dy) * 68 + xx + dx) * 128;
        #pragma unroll
        for (int c16 = 0; c16 < 16; ++c16) {
            f16x8 v = *(const f16x8*)&hp[c16 * 8];
            #pragma unroll
            for (int e = 0; e < 8; ++e) {
                float hv = (float)v[e];
                const float* wp = &swc[(size_t)(tap * 128 + c16 * 8 + e) * 8];
                acc[0] = fmaf(hv, wp[0], acc[0]);
                acc[1] = fmaf(hv, wp[1], acc[1]);
                acc[2] = fmaf(hv, wp[2], acc[2]);
                acc[3] = fmaf(hv, wp[3], acc[3]);
                acc[4] = fmaf(hv, wp[4], acc[4]);
            }
        }
    }
    float m = acc[0];
    #pragma unroll
    for (int cls = 1; cls < 5; ++cls) m = fmaxf(m, acc[cls]);
    float s = 0.f;
    #pragma unroll
    for (int cls = 0; cls < 5; ++cls) s += __expf(acc[cls] - m);
    float lse = logf(s) + m;
    #pragma unroll
    for (int cls = 0; cls < 5; ++cls)
        out[((size_t)(b * 5 + cls) << 12) + (y << 6) + xx] = acc[cls] - lse;
}

extern "C" void kernel_launch(void* const* d_in, const int* in_sizes, int n_in,
                              void* d_out, int out_size, void* d_ws, size_t ws_size,
                              hipStream_t stream) {
    const float* x      = (const float*)d_in[0];
    const float* w_lstm = (const float*)d_in[1];
    const float* b_lstm = (const float*)d_in[2];
    const float* w_conv = (const float*)d_in[3];
    const float* b_conv = (const float*)d_in[4];
    char* ws = (char*)d_ws;
    f16*   wT2 = (f16*)(ws + OFF_WT2);
    float* wc  = (float*)(ws + OFF_WC);
    f16*   xp  = (f16*)(ws + OFF_XP);
    f16*   hA  = (f16*)(ws + OFF_HA);
    f16*   hB  = (f16*)(ws + OFF_HB);
    float* c   = (float*)(ws + OFF_C);

    zero_kernel<<<2048, 256, 0, stream>>>((float4*)(ws + OFF_XP), (int)(ZERO_BYTES / 16));
    wprep<<<3552, 256, 0, stream>>>(w_lstm, wT2);
    wcprep<<<36, 256, 0, stream>>>(w_conv, wc);

    for (int t = 0; t < TT; ++t) {
        const f16* hin  = (t & 1) ? hB : hA;
        f16*       hout = (t & 1) ? hA : hB;
        xprep<<<128, 256, 0, stream>>>(x, xp, t);
        gemm_step<<<1024, 512, 0, stream>>>(xp, hin, wT2, b_lstm, c, hout);
    }
    final_conv<<<128, 256, 0, stream>>>(hA, wc, b_conv, (float*)d_out);
}

// Round 9
// 986.350 us; speedup vs baseline: 11.5080x; 1.1743x over previous
//
#include <hip/hip_runtime.h>
#include <math.h>

#define BB   8
#define TT   12

typedef _Float16 f16;
typedef f16  f16x8 __attribute__((ext_vector_type(8)));
typedef float f32x4 __attribute__((ext_vector_type(4)));

// ws layout (byte offsets) — halo image is 66*68 = 4488 positions
#define OFF_WT2  0ull            // 8*6*64*296*2        = 1,818,624
#define OFF_WC   1818624ull      // 9*128*8*4           = 36,864    -> 1,855,488
#define OFF_XP   1855488ull      // 8*66*68*64*2        = 4,595,712 -> 6,451,200
#define OFF_HA   6451200ull      // 8*66*68*128*2       = 9,191,424 -> 15,642,624
#define OFF_HB   15642624ull     // 9,191,424           -> 24,834,048
#define OFF_C    24834048ull     // 8*64*64*128*4       = 16,777,216 -> 41,611,264
#define WS_END   41611264ull
#define ZERO_BYTES (WS_END - OFF_XP)   // xp + hA + hB + c = 39,755,776

#define A_BYTES 52800            // 660 pos * 40 f16 * 2B (10 rows x 66 cols)
#define B_BYTES 37888            // 64 co * 296 k * 2B

__device__ inline void gload16(const void* g, void* l) {
    // LDS dest is the WAVE-UNIFORM base; HW adds lane*16.
    __builtin_amdgcn_global_load_lds((const __attribute__((address_space(1))) void*)g,
                                     (__attribute__((address_space(3))) void*)l, 16, 0, 0);
}

__device__ inline float sigm_fast(float x) {
    return 1.f / (1.f + __expf(-x));
}
__device__ inline float tanh_fast(float x) {
    float xx = fminf(fmaxf(x, -15.f), 15.f);
    float e = __expf(2.f * xx);
    return (e - 1.f) / (e + 1.f);
}

__global__ __launch_bounds__(256) void zero_kernel(float4* __restrict__ p, int n4) {
    int i = blockIdx.x * blockDim.x + threadIdx.x;
    int stride = gridDim.x * blockDim.x;
    for (; i < n4; i += stride) p[i] = make_float4(0.f, 0.f, 0.f, 0.f);
}

// w_lstm (512,192,3,3) fp32 -> wT2 f16 [ntile(8)][chunk(6)][co_l(64)][k(296 pad)]
// co' = hid*4+gate, k = tap*32 + ci_l (k>=288 zero pad)
__global__ __launch_bounds__(256) void wprep(const float* __restrict__ w, f16* __restrict__ wT2) {
    int t = blockIdx.x * 256 + threadIdx.x;
    if (t >= 8 * 6 * 64 * 296) return;
    int k    = t % 296;
    int r    = t / 296;
    int co_l = r & 63;
    int r2   = r >> 6;
    int chunk = r2 % 6;
    int ntl   = r2 / 6;
    f16 val = (f16)0.f;
    if (k < 288) {
        int tap = k >> 5, ci_l = k & 31;
        int ci  = chunk * 32 + ci_l;          // concat(x:0..63, h:64..191) order
        int cop = ntl * 64 + co_l;
        int hid = cop >> 2, gate = cop & 3;
        val = (f16)w[((size_t)(gate * 128 + hid) * 192 + ci) * 9 + tap];
    }
    wT2[t] = val;
}

// w_conv (5,128,3,3) -> wc f32 [tap(9)][ci(128)][8] (cls padded)
__global__ __launch_bounds__(256) void wcprep(const float* __restrict__ w, float* __restrict__ wc) {
    int t = blockIdx.x * 256 + threadIdx.x;
    if (t >= 9216) return;
    int cls = t & 7, ci = (t >> 3) & 127, tap = t >> 10;
    wc[t] = (cls < 5) ? w[(size_t)(cls * 128 + ci) * 9 + tap] : 0.f;
}

// x_t NCHW fp32 -> NHWC f16 with halo: xp[b][y+1][x+1][ci], dims [8][66][68][64]
__global__ __launch_bounds__(256) void xprep(const float* __restrict__ x, f16* __restrict__ xp, int t) {
    int pos = blockIdx.x * 256 + threadIdx.x;     // 32768
    int b = pos >> 12, rr = pos & 4095, y = rr >> 6, xx = rr & 63;
    const float* s = x + ((size_t)(b * TT + t) * 64) * 4096 + y * 64 + xx;
    f16* d = xp + (((size_t)b * 66 + y + 1) * 68 + xx + 1) * 64;
    #pragma unroll
    for (int c8 = 0; c8 < 8; ++c8) {
        f16x8 v;
        #pragma unroll
        for (int e = 0; e < 8; ++e) v[e] = (f16)s[(size_t)(c8 * 8 + e) * 4096];
        *(f16x8*)&d[c8 * 8] = v;
    }
}

__device__ inline float pickc(f32x4 v, int j) {
    return j == 0 ? v[0] : j == 1 ? v[1] : j == 2 ? v[2] : v[3];
}

// Fused gates-GEMM (implicit im2col, f16 MFMA) + LSTM pointwise epilogue.
// Block: 512 pos (8 image rows) x 64 co'. 8 waves, each wave = 1 image row x 64 co'
// (4 mf x 4 nf square-ish tile -> 0.5 ds_reads per MFMA).
// A single-buffered reg-staged; B double-buffered via global_load_lds.
// bid = nt*64 + mt: the 8 nt-sharers of an mt slab are == mt (mod 8) -> same XCD.
__global__ __launch_bounds__(512, 2) void gemm_step(
    const f16* __restrict__ xp, const f16* __restrict__ hin,
    const f16* __restrict__ wT2, const float* __restrict__ b_lstm,
    float* __restrict__ c_st, f16* __restrict__ hout)
{
    __shared__ __align__(16) char smem[A_BYTES + 2 * B_BYTES];   // 128,576 B
    f16* As  = (f16*)smem;
    char* Bs0 = smem + A_BYTES;
    char* Bs1 = smem + A_BYTES + B_BYTES;

    const int tid  = threadIdx.x;
    const int lane = tid & 63;
    const int wid  = tid >> 6;                // 0..7 = image row within slab
    const int l15  = lane & 15, lg = lane >> 4;

    const int bid = blockIdx.x;
    const int nt  = bid >> 6;                 // 0..7
    const int mt  = bid & 63;                 // 0..63
    const int b   = mt >> 3;
    const int yr  = (mt & 7) << 3;            // first image row of 8-row slab

    const int rowbase = (b * 66 + yr) * 68;   // halo-image position base
    const f16* wslice = wT2 + (size_t)(nt * 6) * 18944;

    f32x4 acc[4][4] = {};
    f16x8 areg[6];

    // ---- hoisted im2col addressing (chunk-invariant): 2640 items = 660 pc x 4 ci8
    int po[6], wo[6], c8o[6];
    bool av[6];
    #pragma unroll
    for (int i = 0; i < 6; ++i) {
        int idx = i * 512 + tid;
        av[i] = idx < 2640;
        int ci8 = idx & 3;
        int pc  = idx >> 2;                 // 0..659 = r*66+c
        int r   = (pc * 497) >> 15;         // /66 exact for pc<660
        int c   = pc - r * 66;
        po[i]  = rowbase + r * 68 + c;
        c8o[i] = ci8 * 8;
        wo[i]  = pc * 40 + ci8 * 8;
    }

    auto loadA = [&](int cc) {
        if (cc < 2) {
            const f16* src = xp + cc * 32;
            #pragma unroll
            for (int i = 0; i < 6; ++i)
                if (av[i]) areg[i] = *(const f16x8*)(src + ((size_t)po[i] << 6) + c8o[i]);
        } else {
            const f16* src = hin + (cc * 32 - 64);
            #pragma unroll
            for (int i = 0; i < 6; ++i)
                if (av[i]) areg[i] = *(const f16x8*)(src + ((size_t)po[i] << 7) + c8o[i]);
        }
    };
    auto writeA = [&]() {
        #pragma unroll
        for (int i = 0; i < 6; ++i)
            if (av[i]) *(f16x8*)&As[wo[i]] = areg[i];
    };
    auto stageB = [&](int cc, char* Bs) {
        const char* bsrc = (const char*)(wslice + (size_t)cc * 18944);
        for (int k = wid; k < 37; k += 8)           // 37*1024 = 37888 B
            gload16(bsrc + k * 1024 + lane * 16, Bs + k * 1024);
    };
    auto compute = [&](const f16* Bsf) {
        #pragma unroll
        for (int tap = 0; tap < 9; ++tap) {
            const int dy = tap / 3, dx = tap - dy * 3;
            f16x8 a[4];
            #pragma unroll
            for (int mf = 0; mf < 4; ++mf)
                a[mf] = *(const f16x8*)&As[((wid + dy) * 66 + mf * 16 + l15 + dx) * 40 + lg * 8];
            f16x8 bf[4];
            #pragma unroll
            for (int nf = 0; nf < 4; ++nf)
                bf[nf] = *(const f16x8*)&Bsf[(nf * 16 + l15) * 296 + tap * 32 + lg * 8];
            #pragma unroll
            for (int mf = 0; mf < 4; ++mf)
                #pragma unroll
                for (int nf = 0; nf < 4; ++nf)
                    acc[mf][nf] = __builtin_amdgcn_mfma_f32_16x16x32_f16(a[mf], bf[nf], acc[mf][nf], 0, 0, 0);
        }
    };

    // ---- prologue: stage chunk 0 ----
    loadA(0);
    stageB(0, Bs0);
    writeA();
    __syncthreads();

    char* Bcur = Bs0; char* Balt = Bs1;

    #pragma unroll 1
    for (int cc = 0; cc < 6; ++cc) {
        if (cc < 5) {
            stageB(cc + 1, Balt);     // async into alt buffer (last read 2 barriers ago)
            loadA(cc + 1);            // global->reg, in flight during compute
        }
        compute((const f16*)Bcur);
        if (cc < 5) {
            __syncthreads();          // all waves done reading As (and Bcur)
            writeA();                 // overwrite single A buffer
            __syncthreads();          // A writes + Balt gloads visible
            char* tb = Bcur; Bcur = Balt; Balt = tb;
        }
    }

    // ---- LSTM epilogue: 4-gate exchange via shfl_xor within 4-lane groups ----
    const int q = lane & 3;   // gate index of this lane's column (co' = hid*4+gate)
    #pragma unroll
    for (int mf = 0; mf < 4; ++mf) {
        #pragma unroll
        for (int nf = 0; nf < 4; ++nf) {
            int hid = nt * 16 + nf * 4 + (l15 >> 2);
            float bias = b_lstm[q * 128 + hid];
            f32x4 v = acc[mf][nf];
            v[0] += bias; v[1] += bias; v[2] += bias; v[3] += bias;
            float own = pickc(v, q);
            float r1 = __shfl_xor(pickc(v, q ^ 1), 1);
            float r2 = __shfl_xor(pickc(v, q ^ 2), 2);
            float r3 = __shfl_xor(pickc(v, q ^ 3), 3);
            float gi = q == 0 ? own : (q == 1 ? r1 : q == 2 ? r2 : r3);
            float gf = q == 1 ? own : (q == 0 ? r1 : q == 3 ? r2 : r3);
            float go = q == 2 ? own : (q == 3 ? r1 : q == 0 ? r2 : r3);
            float gg = q == 3 ? own : (q == 2 ? r1 : q == 1 ? r2 : r3);
            float i_ = sigm_fast(gi);
            float f_ = sigm_fast(gf);
            float o_ = sigm_fast(go);
            float g_ = tanh_fast(gg);
            int px = mf * 16 + lg * 4 + q;         // C row = lg*4 + reg(q)
            int py = yr + wid;
            size_t ic = (((size_t)b * 64 + py) * 64 + px) * 128 + hid;
            float cv = f_ * c_st[ic] + i_ * g_;
            c_st[ic] = cv;
            float hv = o_ * tanh_fast(cv);
            hout[(((size_t)b * 66 + py + 1) * 68 + (px + 1)) * 128 + hid] = (f16)hv;
        }
    }
}

// Final 3x3 conv (128 -> 5) over NHWC f16 h + channelwise log_softmax (NCHW out)
__global__ __launch_bounds__(256) void final_conv(
    const f16* __restrict__ h, const float* __restrict__ wc,
    const float* __restrict__ b_conv, float* __restrict__ out)
{
    __shared__ float swc[9216];
    for (int i = threadIdx.x; i < 9216; i += 256) swc[i] = wc[i];
    __syncthreads();
    int pos = blockIdx.x * 256 + threadIdx.x;
    int b = pos >> 12, rr = pos & 4095, y = rr >> 6, xx = rr & 63;
    float acc[5];
    #pragma unroll
    for (int cls = 0; cls < 5; ++cls) acc[cls] = b_conv[cls];
    #pragma unroll 1
    for (int tap = 0; tap < 9; ++tap) {
        int dy = tap / 3, dx = tap - dy * 3;
        const f16* hp = h + (((size_t)b * 66 + y + dy) * 68 + xx + dx) * 128;
        #pragma unroll
        for (int c16 = 0; c16 < 16; ++c16) {
            f16x8 v = *(const f16x8*)&hp[c16 * 8];
            #pragma unroll
            for (int e = 0; e < 8; ++e) {
                float hv = (float)v[e];
                const float* wp = &swc[(size_t)(tap * 128 + c16 * 8 + e) * 8];
                acc[0] = fmaf(hv, wp[0], acc[0]);
                acc[1] = fmaf(hv, wp[1], acc[1]);
                acc[2] = fmaf(hv, wp[2], acc[2]);
                acc[3] = fmaf(hv, wp[3], acc[3]);
                acc[4] = fmaf(hv, wp[4], acc[4]);
            }
        }
    }
    float m = acc[0];
    #pragma unroll
    for (int cls = 1; cls < 5; ++cls) m = fmaxf(m, acc[cls]);
    float s = 0.f;
    #pragma unroll
    for (int cls = 0; cls < 5; ++cls) s += __expf(acc[cls] - m);
    float lse = logf(s) + m;
    #pragma unroll
    for (int cls = 0; cls < 5; ++cls)
        out[((size_t)(b * 5 + cls) << 12) + (y << 6) + xx] = acc[cls] - lse;
}

extern "C" void kernel_launch(void* const* d_in, const int* in_sizes, int n_in,
                              void* d_out, int out_size, void* d_ws, size_t ws_size,
                              hipStream_t stream) {
    const float* x      = (const float*)d_in[0];
    const float* w_lstm = (const float*)d_in[1];
    const float* b_lstm = (const float*)d_in[2];
    const float* w_conv = (const float*)d_in[3];
    const float* b_conv = (const float*)d_in[4];
    char* ws = (char*)d_ws;
    f16*   wT2 = (f16*)(ws + OFF_WT2);
    float* wc  = (float*)(ws + OFF_WC);
    f16*   xp  = (f16*)(ws + OFF_XP);
    f16*   hA  = (f16*)(ws + OFF_HA);
    f16*   hB  = (f16*)(ws + OFF_HB);
    float* c   = (float*)(ws + OFF_C);

    zero_kernel<<<2048, 256, 0, stream>>>((float4*)(ws + OFF_XP), (int)(ZERO_BYTES / 16));
    wprep<<<3552, 256, 0, stream>>>(w_lstm, wT2);
    wcprep<<<36, 256, 0, stream>>>(w_conv, wc);

    for (int t = 0; t < TT; ++t) {
        const f16* hin  = (t & 1) ? hB : hA;
        f16*       hout = (t & 1) ? hA : hB;
        xprep<<<128, 256, 0, stream>>>(x, xp, t);
        gemm_step<<<512, 512, 0, stream>>>(xp, hin, wT2, b_lstm, c, hout);
    }
    final_conv<<<128, 256, 0, stream>>>(hA, wc, b_conv, (float*)d_out);
}

// Round 10
// 947.250 us; speedup vs baseline: 11.9831x; 1.0413x over previous
//
#include <hip/hip_runtime.h>
#include <math.h>

#define BB   8
#define TT   12

typedef _Float16 f16;
typedef f16  f16x8 __attribute__((ext_vector_type(8)));
typedef float f32x4 __attribute__((ext_vector_type(4)));

// ws layout (byte offsets) — halo image is 66*68 = 4488 positions
#define OFF_WT2  0ull            // 8*6*64*296*2        = 1,818,624
#define OFF_WC   1818624ull      // 9*128*8*4           = 36,864    -> 1,855,488
#define OFF_XP   1855488ull      // 8*66*68*64*2        = 4,595,712 -> 6,451,200
#define OFF_HA   6451200ull      // 8*66*68*128*2       = 9,191,424 -> 15,642,624
#define OFF_HB   15642624ull     // 9,191,424           -> 24,834,048
#define OFF_C    24834048ull     // 8*64*64*128*4       = 16,777,216 -> 41,611,264
#define WS_END   41611264ull
#define ZERO_BYTES (WS_END - OFF_XP)   // xp + hA + hB + c = 39,755,776

#define A_BYTES 31680            // 396 pos * 40 f16 * 2B (6 rows x 66 cols)
#define B_BYTES 37888            // 64 co * 296 k * 2B

__device__ inline void gload16(const void* g, void* l) {
    // LDS dest is the WAVE-UNIFORM base; HW adds lane*16.
    __builtin_amdgcn_global_load_lds((const __attribute__((address_space(1))) void*)g,
                                     (__attribute__((address_space(3))) void*)l, 16, 0, 0);
}

__device__ inline float sigm_fast(float x) {
    return 1.f / (1.f + __expf(-x));
}
__device__ inline float tanh_fast(float x) {
    float xx = fminf(fmaxf(x, -15.f), 15.f);
    float e = __expf(2.f * xx);
    return (e - 1.f) / (e + 1.f);
}

__global__ __launch_bounds__(256) void zero_kernel(float4* __restrict__ p, int n4) {
    int i = blockIdx.x * blockDim.x + threadIdx.x;
    int stride = gridDim.x * blockDim.x;
    for (; i < n4; i += stride) p[i] = make_float4(0.f, 0.f, 0.f, 0.f);
}

// w_lstm (512,192,3,3) fp32 -> wT2 f16 [ntile(8)][chunk(6)][co_l(64)][k(296 pad)]
// co' = hid*4+gate, k = tap*32 + ci_l (k>=288 zero pad)
__global__ __launch_bounds__(256) void wprep(const float* __restrict__ w, f16* __restrict__ wT2) {
    int t = blockIdx.x * 256 + threadIdx.x;
    if (t >= 8 * 6 * 64 * 296) return;
    int k    = t % 296;
    int r    = t / 296;
    int co_l = r & 63;
    int r2   = r >> 6;
    int chunk = r2 % 6;
    int ntl   = r2 / 6;
    f16 val = (f16)0.f;
    if (k < 288) {
        int tap = k >> 5, ci_l = k & 31;
        int ci  = chunk * 32 + ci_l;          // concat(x:0..63, h:64..191) order
        int cop = ntl * 64 + co_l;
        int hid = cop >> 2, gate = cop & 3;
        val = (f16)w[((size_t)(gate * 128 + hid) * 192 + ci) * 9 + tap];
    }
    wT2[t] = val;
}

// w_conv (5,128,3,3) -> wc f32 [tap(9)][ci(128)][8] (cls padded)
__global__ __launch_bounds__(256) void wcprep(const float* __restrict__ w, float* __restrict__ wc) {
    int t = blockIdx.x * 256 + threadIdx.x;
    if (t >= 9216) return;
    int cls = t & 7, ci = (t >> 3) & 127, tap = t >> 10;
    wc[t] = (cls < 5) ? w[(size_t)(cls * 128 + ci) * 9 + tap] : 0.f;
}

// x_t NCHW fp32 -> NHWC f16 with halo: xp[b][y+1][x+1][ci], dims [8][66][68][64]
__global__ __launch_bounds__(256) void xprep(const float* __restrict__ x, f16* __restrict__ xp, int t) {
    int pos = blockIdx.x * 256 + threadIdx.x;     // 32768
    int b = pos >> 12, rr = pos & 4095, y = rr >> 6, xx = rr & 63;
    const float* s = x + ((size_t)(b * TT + t) * 64) * 4096 + y * 64 + xx;
    f16* d = xp + (((size_t)b * 66 + y + 1) * 68 + xx + 1) * 64;
    #pragma unroll
    for (int c8 = 0; c8 < 8; ++c8) {
        f16x8 v;
        #pragma unroll
        for (int e = 0; e < 8; ++e) v[e] = (f16)s[(size_t)(c8 * 8 + e) * 4096];
        *(f16x8*)&d[c8 * 8] = v;
    }
}

__device__ inline float pickc(f32x4 v, int j) {
    return j == 0 ? v[0] : j == 1 ? v[1] : j == 2 ? v[2] : v[3];
}

// Fused gates-GEMM (implicit im2col, f16 MFMA) + LSTM pointwise epilogue.
// Block: 256 pos (4 image rows) x 64 co'. 4 waves, each wave = 1 image row x 64 co'.
// LDS 69.6 KB -> 2 independent blocks per CU: one block's compute fills the
// other's barrier drains (m97/m114-style implicit overlap).
// A reg-prefetched across the barrier; B single-buffered (staged post-barrier,
// exposure covered by the partner block).
// bid = nt*128 + mt: the 8 nt-sharers of an mt slab are == mt (mod 8) -> same XCD.
__global__ __launch_bounds__(256, 2) void gemm_step(
    const f16* __restrict__ xp, const f16* __restrict__ hin,
    const f16* __restrict__ wT2, const float* __restrict__ b_lstm,
    float* __restrict__ c_st, f16* __restrict__ hout)
{
    __shared__ __align__(16) char smem[A_BYTES + B_BYTES];   // 69,568 B
    f16* As = (f16*)smem;
    char* Bs = smem + A_BYTES;

    const int tid  = threadIdx.x;
    const int lane = tid & 63;
    const int wid  = tid >> 6;                // 0..3 = image row within slab
    const int l15  = lane & 15, lg = lane >> 4;

    const int bid = blockIdx.x;
    const int nt  = bid >> 7;                 // 0..7
    const int mt  = bid & 127;                // 0..127
    const int b   = mt >> 4;
    const int yr  = (mt & 15) << 2;           // first image row of 4-row slab

    const int rowbase = (b * 66 + yr) * 68;   // halo-image position base
    const f16* wslice = wT2 + (size_t)(nt * 6) * 18944;

    f32x4 acc[4][4] = {};
    f16x8 areg[7];

    // ---- hoisted im2col addressing (chunk-invariant): 1584 items = 396 pc x 4 ci8
    int po[7], wo[7], c8o[7];
    bool av[7];
    #pragma unroll
    for (int i = 0; i < 7; ++i) {
        int idx = i * 256 + tid;
        av[i] = idx < 1584;
        int ci8 = idx & 3;
        int pc  = idx >> 2;                 // 0..395 = r*66+c
        int r   = (pc * 497) >> 15;         // /66 exact for pc<396
        int c   = pc - r * 66;
        po[i]  = rowbase + r * 68 + c;
        c8o[i] = ci8 * 8;
        wo[i]  = pc * 40 + ci8 * 8;
    }

    auto loadA = [&](int cc) {
        if (cc < 2) {
            const f16* src = xp + cc * 32;
            #pragma unroll
            for (int i = 0; i < 7; ++i)
                if (av[i]) areg[i] = *(const f16x8*)(src + ((size_t)po[i] << 6) + c8o[i]);
        } else {
            const f16* src = hin + (cc * 32 - 64);
            #pragma unroll
            for (int i = 0; i < 7; ++i)
                if (av[i]) areg[i] = *(const f16x8*)(src + ((size_t)po[i] << 7) + c8o[i]);
        }
    };
    auto writeA = [&]() {
        #pragma unroll
        for (int i = 0; i < 7; ++i)
            if (av[i]) *(f16x8*)&As[wo[i]] = areg[i];
    };
    auto stageB = [&](int cc) {
        const char* bsrc = (const char*)(wslice + (size_t)cc * 18944);
        for (int k = wid; k < 37; k += 4)           // 37*1024 = 37888 B
            gload16(bsrc + k * 1024 + lane * 16, Bs + k * 1024);
    };
    auto compute = [&]() {
        const f16* Bsf = (const f16*)Bs;
        #pragma unroll
        for (int tap = 0; tap < 9; ++tap) {
            const int dy = tap / 3, dx = tap - dy * 3;
            f16x8 a[4];
            #pragma unroll
            for (int mf = 0; mf < 4; ++mf)
                a[mf] = *(const f16x8*)&As[((wid + dy) * 66 + mf * 16 + l15 + dx) * 40 + lg * 8];
            f16x8 bf[4];
            #pragma unroll
            for (int nf = 0; nf < 4; ++nf)
                bf[nf] = *(const f16x8*)&Bsf[(nf * 16 + l15) * 296 + tap * 32 + lg * 8];
            #pragma unroll
            for (int mf = 0; mf < 4; ++mf)
                #pragma unroll
                for (int nf = 0; nf < 4; ++nf)
                    acc[mf][nf] = __builtin_amdgcn_mfma_f32_16x16x32_f16(a[mf], bf[nf], acc[mf][nf], 0, 0, 0);
        }
    };

    // ---- prologue: stage chunk 0 ----
    loadA(0);
    stageB(0);
    writeA();
    __syncthreads();

    #pragma unroll 1
    for (int cc = 0; cc < 6; ++cc) {
        if (cc < 5) loadA(cc + 1);    // global->reg, in flight during compute
        compute();
        if (cc < 5) {
            __syncthreads();          // all waves done reading As & Bs
            stageB(cc + 1);           // DMA into B (single buffer, now safe)
            writeA();                 // ds_write prefetched A regs
            __syncthreads();          // drains gloads + A writes
        }
    }

    // ---- LSTM epilogue: 4-gate exchange via shfl_xor within 4-lane groups ----
    const int q = lane & 3;   // gate index of this lane's column (co' = hid*4+gate)
    #pragma unroll
    for (int mf = 0; mf < 4; ++mf) {
        #pragma unroll
        for (int nf = 0; nf < 4; ++nf) {
            int hid = nt * 16 + nf * 4 + (l15 >> 2);
            float bias = b_lstm[q * 128 + hid];
            f32x4 v = acc[mf][nf];
            v[0] += bias; v[1] += bias; v[2] += bias; v[3] += bias;
            float own = pickc(v, q);
            float r1 = __shfl_xor(pickc(v, q ^ 1), 1);
            float r2 = __shfl_xor(pickc(v, q ^ 2), 2);
            float r3 = __shfl_xor(pickc(v, q ^ 3), 3);
            float gi = q == 0 ? own : (q == 1 ? r1 : q == 2 ? r2 : r3);
            float gf = q == 1 ? own : (q == 0 ? r1 : q == 3 ? r2 : r3);
            float go = q == 2 ? own : (q == 3 ? r1 : q == 0 ? r2 : r3);
            float gg = q == 3 ? own : (q == 2 ? r1 : q == 1 ? r2 : r3);
            float i_ = sigm_fast(gi);
            float f_ = sigm_fast(gf);
            float o_ = sigm_fast(go);
            float g_ = tanh_fast(gg);
            int px = mf * 16 + lg * 4 + q;         // C row = lg*4 + reg(q)
            int py = yr + wid;
            size_t ic = (((size_t)b * 64 + py) * 64 + px) * 128 + hid;
            float cv = f_ * c_st[ic] + i_ * g_;
            c_st[ic] = cv;
            float hv = o_ * tanh_fast(cv);
            hout[(((size_t)b * 66 + py + 1) * 68 + (px + 1)) * 128 + hid] = (f16)hv;
        }
    }
}

// Final 3x3 conv (128 -> 5) over NHWC f16 h + channelwise log_softmax (NCHW out)
__global__ __launch_bounds__(256) void final_conv(
    const f16* __restrict__ h, const float* __restrict__ wc,
    const float* __restrict__ b_conv, float* __restrict__ out)
{
    __shared__ float swc[9216];
    for (int i = threadIdx.x; i < 9216; i += 256) swc[i] = wc[i];
    __syncthreads();
    int pos = blockIdx.x * 256 + threadIdx.x;
    int b = pos >> 12, rr = pos & 4095, y = rr >> 6, xx = rr & 63;
    float acc[5];
    #pragma unroll
    for (int cls = 0; cls < 5; ++cls) acc[cls] = b_conv[cls];
    #pragma unroll 1
    for (int tap = 0; tap < 9; ++tap) {
        int dy = tap / 3, dx = tap - dy * 3;
        const f16* hp = h + (((size_t)b * 66 + y + dy) * 68 + xx + dx) * 128;
        #pragma unroll
        for (int c16 = 0; c16 < 16; ++c16) {
            f16x8 v = *(const f16x8*)&hp[c16 * 8];
            #pragma unroll
            for (int e = 0; e < 8; ++e) {
                float hv = (float)v[e];
                const float* wp = &swc[(size_t)(tap * 128 + c16 * 8 + e) * 8];
                acc[0] = fmaf(hv, wp[0], acc[0]);
                acc[1] = fmaf(hv, wp[1], acc[1]);
                acc[2] = fmaf(hv, wp[2], acc[2]);
                acc[3] = fmaf(hv, wp[3], acc[3]);
                acc[4] = fmaf(hv, wp[4], acc[4]);
            }
        }
    }
    float m = acc[0];
    #pragma unroll
    for (int cls = 1; cls < 5; ++cls) m = fmaxf(m, acc[cls]);
    float s = 0.f;
    #pragma unroll
    for (int cls = 0; cls < 5; ++cls) s += __expf(acc[cls] - m);
    float lse = logf(s) + m;
    #pragma unroll
    for (int cls = 0; cls < 5; ++cls)
        out[((size_t)(b * 5 + cls) << 12) + (y << 6) + xx] = acc[cls] - lse;
}

extern "C" void kernel_launch(void* const* d_in, const int* in_sizes, int n_in,
                              void* d_out, int out_size, void* d_ws, size_t ws_size,
                              hipStream_t stream) {
    const float* x      = (const float*)d_in[0];
    const float* w_lstm = (const float*)d_in[1];
    const float* b_lstm = (const float*)d_in[2];
    const float* w_conv = (const float*)d_in[3];
    const float* b_conv = (const float*)d_in[4];
    char* ws = (char*)d_ws;
    f16*   wT2 = (f16*)(ws + OFF_WT2);
    float* wc  = (float*)(ws + OFF_WC);
    f16*   xp  = (f16*)(ws + OFF_XP);
    f16*   hA  = (f16*)(ws + OFF_HA);
    f16*   hB  = (f16*)(ws + OFF_HB);
    float* c   = (float*)(ws + OFF_C);

    zero_kernel<<<2048, 256, 0, stream>>>((float4*)(ws + OFF_XP), (int)(ZERO_BYTES / 16));
    wprep<<<3552, 256, 0, stream>>>(w_lstm, wT2);
    wcprep<<<36, 256, 0, stream>>>(w_conv, wc);

    for (int t = 0; t < TT; ++t) {
        const f16* hin  = (t & 1) ? hB : hA;
        f16*       hout = (t & 1) ? hA : hB;
        xprep<<<128, 256, 0, stream>>>(x, xp, t);
        gemm_step<<<1024, 256, 0, stream>>>(xp, hin, wT2, b_lstm, c, hout);
    }
    final_conv<<<128, 256, 0, stream>>>(hA, wc, b_conv, (float*)d_out);
}